// Round 6
// baseline (393.065 us; speedup 1.0000x reference)
//
#include <hip/hip_runtime.h>
#include <math.h>

// Problem constants (fixed by the reference)
#define N_NODES 1024
#define BATCH   8
#define FEAT    128        // F == O
#define NDIR    3
#define NB      (N_NODES*BATCH)   // 8192
#define G3      384               // 3*O

typedef __bf16 bf16_t;
using bf16x8 = __attribute__((ext_vector_type(8))) __bf16;
using bf16x4 = __attribute__((ext_vector_type(4))) __bf16;
using f32x4  = __attribute__((ext_vector_type(4))) float;

// async global->LDS 16B per lane; LDS dest must be wave-uniform base (+lane*16)
#define GLOAD_LDS16(g, l) \
    __builtin_amdgcn_global_load_lds((const __attribute__((address_space(1))) void*)(g), \
                                     (__attribute__((address_space(3))) void*)(l), 16, 0, 0)

// ---------------------------------------------------------------------------
// 64x64-tile, BK=128 MFMA GEMM helpers. 4 waves; wave w owns m-rows
// [w*16, w*16+16). As/Bs: [64 rows][128 k] bf16 (k-contiguous, 32 KB total).
// Stage: 8 wave-level GLOAD rounds; chunk c = q*4+w covers 4 rows (1 KB).
// ---------------------------------------------------------------------------
#define STAGE128(As, Bs, Arow, Brow, sA, sB, k0, w, lane)                      \
    {                                                                          \
        _Pragma("unroll")                                                      \
        for (int q = 0; q < 4; ++q) {                                          \
            int c = q*4 + (w);                                                 \
            int row = c*4 + ((lane) >> 4), kseg = ((lane) & 15)*8;             \
            GLOAD_LDS16((Arow) + (size_t)row*(sA) + (k0) + kseg,               \
                        (char*)(As) + c*1024);                                 \
            GLOAD_LDS16((Brow) + (size_t)row*(sB) + (k0) + kseg,               \
                        (char*)(Bs) + c*1024);                                 \
        }                                                                      \
    }

#define MFMA128(As, Bs, acc, w, lane)                                          \
    {                                                                          \
        _Pragma("unroll")                                                      \
        for (int ks = 0; ks < 128; ks += 32) {                                 \
            bf16x8 af = *reinterpret_cast<const bf16x8*>(                      \
                &(As)[((w)*16 + ((lane) & 15))*128 + ks + (((lane) >> 4) * 8)]);\
            _Pragma("unroll")                                                  \
            for (int j = 0; j < 4; ++j) {                                      \
                bf16x8 bfv = *reinterpret_cast<const bf16x8*>(                 \
                    &(Bs)[(j*16 + ((lane) & 15))*128 + ks + (((lane) >> 4) * 8)]);\
                (acc)[j] = __builtin_amdgcn_mfma_f32_16x16x32_bf16(af, bfv, (acc)[j], 0, 0, 0); \
            }                                                                  \
        }                                                                      \
    }

// ---------------------------------------------------------------------------
// adj fp32 -> CENTERED bf16 (adj - 0.5)
// ---------------------------------------------------------------------------
__global__ __launch_bounds__(256) void k_cvt_adj(
    const float* __restrict__ src, bf16_t* __restrict__ dst, int n4)
{
    int i = blockIdx.x * 256 + threadIdx.x;
    int stride = gridDim.x * 256;
    for (; i < n4; i += stride) {
        float4 v = reinterpret_cast<const float4*>(src)[i];
        bf16x4 o;
        o[0] = (bf16_t)(v.x - 0.5f); o[1] = (bf16_t)(v.y - 0.5f);
        o[2] = (bf16_t)(v.z - 0.5f); o[3] = (bf16_t)(v.w - 0.5f);
        *reinterpret_cast<bf16x4*>(&dst[(size_t)i * 4]) = o;
    }
}

// ---------------------------------------------------------------------------
// Weight prep, hi/lo split concats (K'=384):
//  m<384: W -> wsup (pattern A [hi|lo|hi]); m in [384,512): Wh -> wsup (A)
//  m in [512,896): Whh -> whhc (A);  m in [896,1280): Wih -> wihc (B [hi|hi|lo])
// ---------------------------------------------------------------------------
__global__ __launch_bounds__(128) void k_wprep(
    const float* __restrict__ W, const float* __restrict__ Wh,
    const float* __restrict__ Whh, const float* __restrict__ Wih,
    bf16_t* __restrict__ wsup,    // [2][512][384]
    bf16_t* __restrict__ whhc,    // [2][384][384]
    bf16_t* __restrict__ wihc)    // [2][384][384]
{
    int m = blockIdx.x, l = blockIdx.y, k = threadIdx.x;
    float w;
    bf16_t* dst;
    bool patB = false;
    if (m < 384) {
        int d = m >> 7, o = m & 127;
        w = W[((size_t)(l*3 + d)*128 + k)*128 + o];
        dst = wsup + ((size_t)l*512 + m)*384;
    } else if (m < 512) {
        int o = m - 384;
        w = Wh[((size_t)l*128 + k)*128 + o];
        dst = wsup + ((size_t)l*512 + m)*384;
    } else if (m < 896) {
        int c = m - 512;
        w = Whh[((size_t)l*384 + c)*128 + k];
        dst = whhc + ((size_t)l*384 + c)*384;
    } else {
        int c = m - 896;
        w = Wih[((size_t)l*384 + c)*128 + k];
        dst = wihc + ((size_t)l*384 + c)*384;
        patB = true;
    }
    bf16_t hi = (bf16_t)w;
    bf16_t lo = (bf16_t)(w - (float)hi);
    if (patB) { dst[k] = hi; dst[128 + k] = hi; dst[256 + k] = lo; }
    else      { dst[k] = hi; dst[128 + k] = lo; dst[256 + k] = hi; }
}

// ---------------------------------------------------------------------------
// x-cat build (layer 0): inputs fp32 [N,B,128] -> xcat [8][1024][384] = [hi|hi|lo]
// ---------------------------------------------------------------------------
__global__ __launch_bounds__(256) void k_xcat(
    const float* __restrict__ X, bf16_t* __restrict__ xcat)
{
    int idx = blockIdx.x * 256 + threadIdx.x;   // over 8192*128
    int k = idx & 127, r = idx >> 7;
    int n = r >> 3, b = r & 7;
    float v = X[idx];
    bf16_t hi = (bf16_t)v;
    bf16_t lo = (bf16_t)(v - (float)hi);
    bf16_t* dst = xcat + ((size_t)(b*1024 + n))*384 + k;
    dst[0] = hi; dst[128] = hi; dst[256] = lo;
}

// ---------------------------------------------------------------------------
// k_sup (64x64, BK=128): C[m][n] = sum_k' wsup[m][k'] * xcat[b][n][k'] (K'=384)
//  m<384 : supt[((m>>7)*8+b)*128 + (m&127)][n] = bf16(C + Bc)
//  m>=384: tbuf[(b*128 + m-384)][n] = relu(C + Bh)  (fp32)
// grid (16 n-tiles, 8 m-tiles, 8 b)
// ---------------------------------------------------------------------------
__global__ __launch_bounds__(256, 4) void k_sup(
    const bf16_t* __restrict__ Wcat,  // [512][384]
    const bf16_t* __restrict__ xcat,  // [8][1024][384]
    const float* __restrict__ Bcl,    // [3,128]
    const float* __restrict__ Bhl,    // [128]
    bf16_t* __restrict__ supt,        // [24][128][1024]
    float* __restrict__ tbuf)         // [8][128][1024]
{
    __shared__ bf16_t As[64*128];
    __shared__ bf16_t Bs[64*128];
    const int t = threadIdx.x, lane = t & 63, w = t >> 6;
    const int n0 = blockIdx.x * 64;
    const int m0 = blockIdx.y * 64;
    const int b  = blockIdx.z;
    const bf16_t* Arow = Wcat + (size_t)m0 * 384;
    const bf16_t* Brow = xcat + ((size_t)b * 1024 + n0) * 384;

    f32x4 acc[4] = {};
    for (int k0 = 0; k0 < 384; k0 += 128) {
        STAGE128(As, Bs, Arow, Brow, 384, 384, k0, w, lane);
        __syncthreads();
        MFMA128(As, Bs, acc, w, lane);
        __syncthreads();
    }
    #pragma unroll
    for (int j = 0; j < 4; ++j) {
        int n = n0 + j*16 + (lane & 15);
        #pragma unroll
        for (int rg = 0; rg < 4; ++rg) {
            int m = m0 + w*16 + (lane >> 4)*4 + rg;
            float v = acc[j][rg];
            if (m < 384) {
                int d = m >> 7, o = m & 127;
                supt[((size_t)((d*8 + b)*128 + o))*1024 + n] = (bf16_t)(v + Bcl[d*128 + o]);
            } else {
                int o = m - 384;
                tbuf[((size_t)(b*128 + o))*1024 + n] = fmaxf(v + Bhl[o], 0.0f);
            }
        }
    }
}

// ---------------------------------------------------------------------------
// colsum[row] = sum_n supt[row][n]  (row = z*128+o, 3072 rows), fp32.
// ---------------------------------------------------------------------------
__global__ __launch_bounds__(256) void k_colsum(
    const bf16_t* __restrict__ supt, float* __restrict__ colsum)
{
    int row = blockIdx.x * 4 + (threadIdx.x >> 6);
    int lane = threadIdx.x & 63;
    const bf16_t* p = supt + (size_t)row * 1024 + lane * 16;
    bf16x8 v0 = *reinterpret_cast<const bf16x8*>(p);
    bf16x8 v1 = *reinterpret_cast<const bf16x8*>(p + 8);
    float s = 0.0f;
    #pragma unroll
    for (int i = 0; i < 8; ++i) s += (float)v0[i] + (float)v1[i];
    #pragma unroll
    for (int off = 32; off > 0; off >>= 1) s += __shfl_down(s, off, 64);
    if (lane == 0) colsum[row] = s;
}

// ---------------------------------------------------------------------------
// k_gh (64x64, BK=128): ghb[r][c] = bf16(sum_k' xcat[r][k']*whhc[c][k'] + bhh)
// grid (128 m-tiles, 6 c-tiles). K'=384.
// ---------------------------------------------------------------------------
__global__ __launch_bounds__(256, 4) void k_gh(
    const bf16_t* __restrict__ A,     // [8192][384] (xcat flat)
    const bf16_t* __restrict__ B,     // [384][384]
    const float* __restrict__ bias,   // [384]
    bf16_t* __restrict__ C)           // [8192][384]
{
    __shared__ bf16_t As[64*128];
    __shared__ bf16_t Bs[64*128];
    const int t = threadIdx.x, lane = t & 63, w = t >> 6;
    const int m0 = blockIdx.x * 64;
    const int c0 = blockIdx.y * 64;
    const bf16_t* Arow = A + (size_t)m0 * 384;
    const bf16_t* Brow = B + (size_t)c0 * 384;

    f32x4 acc[4] = {};
    for (int k0 = 0; k0 < 384; k0 += 128) {
        STAGE128(As, Bs, Arow, Brow, 384, 384, k0, w, lane);
        __syncthreads();
        MFMA128(As, Bs, acc, w, lane);
        __syncthreads();
    }
    #pragma unroll
    for (int j = 0; j < 4; ++j) {
        int c = c0 + j*16 + (lane & 15);
        float bv = bias[c];
        #pragma unroll
        for (int rg = 0; rg < 4; ++rg) {
            int m = m0 + w*16 + (lane >> 4)*4 + rg;
            C[(size_t)m*G3 + c] = (bf16_t)(acc[j][rg] + bv);
        }
    }
}

// ---------------------------------------------------------------------------
// k_agg (64x64, BK=128): agg[z][m][o] = sum_n adjc[z][m][n]*supt[z][o][n]
//                                        + 0.5*colsum[z][o]
// Output aggcat [24576][384] = [hi|lo|hi]. grid (16 m-tiles, 2 o-tiles, 24 z)
// ---------------------------------------------------------------------------
__global__ __launch_bounds__(256, 4) void k_agg(
    const bf16_t* __restrict__ adjb,   // [24][1024][1024] centered
    const bf16_t* __restrict__ supt,   // [24][128][1024]
    const float* __restrict__ colsum,  // [24][128]
    bf16_t* __restrict__ aggcat)       // [24576][384]
{
    __shared__ bf16_t As[64*128];
    __shared__ bf16_t Bs[64*128];
    const int t = threadIdx.x, lane = t & 63, w = t >> 6;
    const int m0 = blockIdx.x * 64;
    const int o0 = blockIdx.y * 64;
    const int z  = blockIdx.z;
    const bf16_t* Arow = adjb + (size_t)z * 1024 * 1024 + (size_t)m0 * 1024;
    const bf16_t* Brow = supt + (size_t)z * 128 * 1024 + (size_t)o0 * 1024;

    f32x4 acc[4] = {};
    for (int k0 = 0; k0 < 1024; k0 += 128) {
        STAGE128(As, Bs, Arow, Brow, 1024, 1024, k0, w, lane);
        __syncthreads();
        MFMA128(As, Bs, acc, w, lane);
        __syncthreads();
    }
    #pragma unroll
    for (int j = 0; j < 4; ++j) {
        int o = o0 + j*16 + (lane & 15);
        float cs = 0.5f * colsum[z*128 + o];
        #pragma unroll
        for (int rg = 0; rg < 4; ++rg) {
            size_t m = (size_t)z*1024 + m0 + w*16 + (lane >> 4)*4 + rg;
            float v = acc[j][rg] + cs;
            bf16_t hi = (bf16_t)v;
            bf16_t lo = (bf16_t)(v - (float)hi);
            bf16_t* row = aggcat + m*384;
            row[o] = hi; row[128 + o] = lo; row[256 + o] = hi;
        }
    }
}

// ---------------------------------------------------------------------------
// k_gi (64x64, BK=128): gi[m][c] = sum_k aggcat[m][k]*wihc[c][k] + bih[c]
// c<256 (i_r,i_z): K=128 (hi*hi only — sigmoid-damped, bf16 out -> girz)
// c>=256 (i_n)   : K=384 (hi/lo exact, fp32 out -> gin)
// grid (384 m-tiles, 6 c-tiles).
// ---------------------------------------------------------------------------
__global__ __launch_bounds__(256, 4) void k_gi(
    const bf16_t* __restrict__ A,      // [24576][384]
    const bf16_t* __restrict__ B,      // [384][384]
    const float*  __restrict__ bias,   // [384]
    bf16_t* __restrict__ girz,         // [24576][256]
    float* __restrict__ gin)           // [24576][128]
{
    __shared__ bf16_t As[64*128];
    __shared__ bf16_t Bs[64*128];
    const int t = threadIdx.x, lane = t & 63, w = t >> 6;
    const int m0 = blockIdx.x * 64;
    const int c0 = blockIdx.y * 64;
    const int K  = (c0 < 256) ? 128 : 384;   // rz gates: hi-only is enough
    const bf16_t* Arow = A + (size_t)m0 * 384;
    const bf16_t* Brow = B + (size_t)c0 * 384;

    f32x4 acc[4] = {};
    for (int k0 = 0; k0 < K; k0 += 128) {
        STAGE128(As, Bs, Arow, Brow, 384, 384, k0, w, lane);
        __syncthreads();
        MFMA128(As, Bs, acc, w, lane);
        __syncthreads();
    }
    #pragma unroll
    for (int j = 0; j < 4; ++j) {
        int c = c0 + j*16 + (lane & 15);
        float bv = bias[c];
        #pragma unroll
        for (int rg = 0; rg < 4; ++rg) {
            int m = m0 + w*16 + (lane >> 4)*4 + rg;
            float v = acc[j][rg] + bv;
            if (c < 256) girz[(size_t)m*256 + c] = (bf16_t)v;
            else         gin[(size_t)m*128 + (c - 256)] = v;
        }
    }
}

// ---------------------------------------------------------------------------
// GRU gates + sum over d + relu + highway blend.
// h reconstructed exactly from xcat (hi+lo). grid (64 n-blocks of 16, 8 b).
// ---------------------------------------------------------------------------
__global__ __launch_bounds__(256) void k_gates(
    const bf16_t* __restrict__ girz, const float* __restrict__ gin,
    const bf16_t* __restrict__ ghb,
    bf16_t* xcat,                       // NOT restrict: read+write same buffer
    const float* __restrict__ tbuf,
    float* __restrict__ Xout, int write_xcat)
{
    __shared__ float ts[128*17];
    const int b = blockIdx.y, n0 = blockIdx.x * 16;
    const int tid = threadIdx.x;
    {
        int o = tid >> 1, nh = (tid & 1) * 8;
        const float* src = tbuf + ((size_t)(b*128 + o))*1024 + n0 + nh;
        float4 v0 = *reinterpret_cast<const float4*>(src);
        float4 v1 = *reinterpret_cast<const float4*>(src + 4);
        float* dst = &ts[o*17 + nh];
        dst[0]=v0.x; dst[1]=v0.y; dst[2]=v0.z; dst[3]=v0.w;
        dst[4]=v1.x; dst[5]=v1.y; dst[6]=v1.z; dst[7]=v1.w;
    }
    __syncthreads();
    #pragma unroll
    for (int p = 0; p < 8; ++p) {
        int e = p*256 + tid;
        int nn = e >> 7, o = e & 127;
        int n = n0 + nn;
        size_t rb = (size_t)(b*1024 + n);
        bf16_t* xr = xcat + rb*384;
        float h = (float)xr[o] + (float)xr[256 + o];
        const bf16_t* ghr = ghb + rb*G3;
        float g_r = (float)ghr[o], g_z = (float)ghr[128+o], g_n = (float)ghr[256+o];
        float acc = 0.0f;
        #pragma unroll
        for (int d = 0; d < 3; ++d) {
            size_t rr = (size_t)((d*8 + b)*1024 + n);
            float i_r = (float)girz[rr*256 + o];
            float i_z = (float)girz[rr*256 + 128 + o];
            float i_n = gin[rr*128 + o];
            float rg = 1.0f / (1.0f + expf(-(i_r + g_r)));
            float zg = 1.0f / (1.0f + expf(-(i_z + g_z)));
            float ng = tanhf(i_n + rg * g_n);
            acc += (1.0f - zg) * ng + zg * h;
        }
        float outv = fmaxf(acc, 0.0f);
        float tg = ts[o*17 + nn];
        float res = outv * tg + h * (1.0f - tg);
        if (Xout) Xout[(size_t)(n*8 + b)*128 + o] = res;
        if (write_xcat) {
            bf16_t hi = (bf16_t)res;
            bf16_t lo = (bf16_t)(res - (float)hi);
            xr[o] = hi; xr[128 + o] = hi; xr[256 + o] = lo;
        }
    }
}

// ---------------------------------------------------------------------------
extern "C" void kernel_launch(void* const* d_in, const int* in_sizes, int n_in,
                              void* d_out, int out_size, void* d_ws, size_t ws_size,
                              hipStream_t stream) {
    const float* inputs = (const float*)d_in[0];   // [1024,8,128]
    const float* adj    = (const float*)d_in[1];   // [3,8,1024,1024]
    const float* W      = (const float*)d_in[2];   // [2,3,128,128]
    const float* Bc     = (const float*)d_in[3];   // [2,3,128]
    const float* Wh     = (const float*)d_in[4];   // [2,128,128]
    const float* Bh     = (const float*)d_in[5];   // [2,128]
    const float* Wih    = (const float*)d_in[6];   // [2,384,128]
    const float* Whh    = (const float*)d_in[7];   // [2,384,128]
    const float* bih    = (const float*)d_in[8];   // [2,384]
    const float* bhh    = (const float*)d_in[9];   // [2,384]

    char* ws = (char*)d_ws;
    float*  tbuf   = (float*)ws;   ws += (size_t)8*128*1024*4;      // 4.19 MB
    bf16_t* xcat   = (bf16_t*)ws;  ws += (size_t)8*1024*384*2;      // 6.29 MB
    bf16_t* ghb    = (bf16_t*)ws;  ws += (size_t)NB*G3*2;           // 6.29 MB
    bf16_t* supt   = (bf16_t*)ws;  ws += (size_t)24*128*1024*2;     // 6.29 MB
    bf16_t* aggcat = (bf16_t*)ws;  ws += (size_t)3*NB*384*2;        // 18.87 MB
    bf16_t* girz   = (bf16_t*)ws;  ws += (size_t)3*NB*256*2;        // 12.58 MB
    float*  gin    = (float*)ws;   ws += (size_t)3*NB*128*4;        // 12.58 MB
    float*  colsum = (float*)ws;   ws += (size_t)24*128*4;          // 12 KB
    bf16_t* wsup   = (bf16_t*)ws;  ws += (size_t)2*512*384*2;       // 0.79 MB
    bf16_t* whhc   = (bf16_t*)ws;  ws += (size_t)2*384*384*2;       // 1.18 MB
    bf16_t* wihc   = (bf16_t*)ws;  ws += (size_t)2*384*384*2;       // 1.18 MB
    bf16_t* adjb   = (bf16_t*)ws;                                   // 50.33 MB

    // one-time preps
    k_cvt_adj<<<dim3(4096), dim3(256), 0, stream>>>(adj, adjb, 3*8*1024*1024/4);
    k_wprep<<<dim3(1280, 2), dim3(128), 0, stream>>>(W, Wh, Whh, Wih, wsup, whhc, wihc);
    k_xcat<<<dim3(4096), dim3(256), 0, stream>>>(inputs, xcat);

    for (int l = 0; l < 2; ++l) {
        // support (bf16 [z][o][n]) + highway t (fp32 [b][o][n])
        k_sup<<<dim3(16, 8, 8), dim3(256), 0, stream>>>(
            wsup + (size_t)l*512*384, xcat, Bc + l*3*128, Bh + l*128, supt, tbuf);
        // column sums of support (for centered-adj correction)
        k_colsum<<<dim3(768), dim3(256), 0, stream>>>(supt, colsum);
        // gh = x @ Whh^T + bhh
        k_gh<<<dim3(128, 6), dim3(256), 0, stream>>>(
            xcat, whhc + (size_t)l*384*384, bhh + l*G3, ghb);
        // agg = adjc @ support + 0.5*colsum, output hi/lo-cat
        k_agg<<<dim3(16, 2, 24), dim3(256), 0, stream>>>(adjb, supt, colsum, aggcat);
        // gi = agg @ Wih^T + bih (rz: K=128, n: K=384 exact)
        k_gi<<<dim3(384, 6), dim3(256), 0, stream>>>(
            aggcat, wihc + (size_t)l*384*384, bih + l*G3, girz, gin);
        // gates + sum_d + relu + highway; layer0 -> xcat update, layer1 -> d_out
        k_gates<<<dim3(64, 8), dim3(256), 0, stream>>>(
            girz, gin, ghb, xcat, tbuf,
            (l == 1) ? (float*)d_out : (float*)nullptr, (l == 0) ? 1 : 0);
    }
}